// Round 6
// baseline (296.132 us; speedup 1.0000x reference)
//
#include <hip/hip_runtime.h>
#include <stdint.h>

typedef unsigned int uint;
typedef unsigned long long ull;

#define HW 3600
#define CDIM 256
#define KNN 64
#define M_REAL 7200
#define PADM 7232          // 7200 padded to multiple of 64 (113*64)
#define QPB 8              // topk queries per block (one per wave)

#define TKB 900            // topk blocks
#define IHB 904            // init_h blocks (2 c-tiles each)
#define SUB 64             // setup blocks

#define LDB2 136           // BK=128 LDS row pitch (shorts)
#define LDG 264            // gather_gemm LDS row pitch (shorts), 528 B (16B-mult)
#define GGB 450            // gather_gemm blocks: 16 query rows each = 7200

using short8  = __attribute__((ext_vector_type(8))) short;
using floatx4 = __attribute__((ext_vector_type(4))) float;

__device__ inline unsigned short f2bf(float f) {   // RNE fp32 -> bf16 bits
    uint u = __float_as_uint(f);
    uint r = u + 0x7FFFu + ((u >> 16) & 1u);
    return (unsigned short)(r >> 16);
}
__device__ inline float bf2f(unsigned short b) {
    return __uint_as_float(((uint)b) << 16);
}

#define WAVE_LDS_FENCE() asm volatile("s_waitcnt lgkmcnt(0)" ::: "memory")

// ---------------------------------------------------------------------------
// wave_select: threshold byte-bin from a 256-bin wave-private histogram.
// ---------------------------------------------------------------------------
__device__ inline void wave_select(uint* hist, uint* s_bin, uint* s_want,
                                   int lane, uint want) {
    uint h0 = hist[4 * lane + 0], h1 = hist[4 * lane + 1];
    uint h2 = hist[4 * lane + 2], h3 = hist[4 * lane + 3];
    hist[4 * lane + 0] = 0; hist[4 * lane + 1] = 0;
    hist[4 * lane + 2] = 0; hist[4 * lane + 3] = 0;
    uint c4 = h0 + h1 + h2 + h3;
    uint v = c4;
    #pragma unroll
    for (int off = 1; off < 64; off <<= 1) {
        uint o = __shfl_up(v, off, 64);
        if (lane >= off) v += o;
    }
    uint below = v - c4;
    if (below < want && want <= v) {
        uint b = 4 * lane, c = below;
        if (c + h0 < want) { c += h0; b = 4 * lane + 1;
            if (c + h1 < want) { c += h1; b = 4 * lane + 2;
                if (c + h2 < want) { c += h2; b = 4 * lane + 3; } } }
        *s_bin = b;
        *s_want = want - c;
    }
}

// ---------------------------------------------------------------------------
// Mega-kernel: round-0 structure verbatim (61 µs measured, VGPR 128).
// Roles: topk [0,900), init_h [900,1804), setup [1804,1868).
// ---------------------------------------------------------------------------
union MegaSmem {
    struct {
        float4 pts[HW];                  // 57600 B
        uint hist[QPB][256];             // 8192 B
        uint s_bin[QPB], s_want[QPB], s_cnt[QPB];
    } tk;
    struct { float tile[2][32][33]; } ih;
};

__global__ __launch_bounds__(512) void mega_kernel(
    const float* __restrict__ points, int* __restrict__ idx_out,
    const float* __restrict__ cnn, unsigned short* __restrict__ NH,
    float* __restrict__ out,
    const float* __restrict__ mw, const float* __restrict__ rw,
    unsigned short* __restrict__ mo, unsigned short* __restrict__ ro) {
    __shared__ MegaSmem sm;
    const int blk = blockIdx.x;

    if (blk >= TKB + IHB) {
        // ---- setup role: weights fp32 -> bf16 ----
        int i0 = (blk - TKB - IHB) * 2048 + threadIdx.x * 4;
        float4 v = *(const float4*)&rw[i0];
        uint2 p;
        p.x = (uint)f2bf(v.x) | ((uint)f2bf(v.y) << 16);
        p.y = (uint)f2bf(v.z) | ((uint)f2bf(v.w) << 16);
        *(uint2*)&ro[i0] = p;
        if (i0 < 65536) {
            float4 m = *(const float4*)&mw[i0];
            p.x = (uint)f2bf(m.x) | ((uint)f2bf(m.y) << 16);
            p.y = (uint)f2bf(m.z) | ((uint)f2bf(m.w) << 16);
            *(uint2*)&mo[i0] = p;
        }
        return;
    }

    if (blk >= TKB) {
        // ---- init_h role: two 32x32 c-tiles per block ----
        const int b = blk - TKB;             // 0..903
        const int n = b / 452;
        const int r = b - n * 452;
        const int hw0 = (r % 113) * 32;
        const int c0 = (r / 113) * 64 + ((threadIdx.x >> 8) << 5);
        const int t8 = threadIdx.x & 255;
        const int tx = t8 & 31;
        const int ty = t8 >> 5;              // 0..7
        float (*tile)[33] = sm.ih.tile[threadIdx.x >> 8];
        const float* __restrict__ src = cnn + (size_t)n * CDIM * HW;
        #pragma unroll
        for (int rr = 0; rr < 4; ++rr) {
            int cc = ty + rr * 8;
            int hw = hw0 + tx;
            if (hw < HW) {
                float v = src[(size_t)(c0 + cc) * HW + hw];
                tile[cc][tx] = v;
                out[(size_t)n * (2 * CDIM * HW) + (size_t)(c0 + cc) * HW + hw] = v;
            }
        }
        __syncthreads();
        #pragma unroll
        for (int rr = 0; rr < 4; ++rr) {
            int hh = ty + rr * 8;
            int hw = hw0 + hh;
            if (hw < HW)
                NH[(size_t)(n * HW + hw) * 512 + c0 + tx] = f2bf(tile[tx][hh]);
        }
        return;
    }

    // ---- topk role ----
    const int wv = threadIdx.x >> 6;
    const int lane = threadIdx.x & 63;
    const int q = blk * QPB + wv;
    const int n = (blk * QPB) / HW;          // batch uniform per block (450 | 8)
    const int i = q - n * HW;

    const float* __restrict__ px = points + (size_t)n * 3 * HW;
    const float* __restrict__ py = px + HW;
    const float* __restrict__ pz = py + HW;

    for (int j = threadIdx.x; j < HW; j += 512)
        sm.tk.pts[j] = make_float4(px[j], py[j], pz[j], 0.0f);
    sm.tk.hist[wv][4 * lane + 0] = 0; sm.tk.hist[wv][4 * lane + 1] = 0;
    sm.tk.hist[wv][4 * lane + 2] = 0; sm.tk.hist[wv][4 * lane + 3] = 0;
    if (lane == 0) sm.tk.s_cnt[wv] = 0;
    __syncthreads();          // the ONLY block barrier: pts is block-shared

    float4 pq = sm.tk.pts[i];
    const float xi = pq.x, yi = pq.y, zi = pq.z;
    const float sqi = xi * xi + yi * yi + zi * zi;

    uint qp[29];
    #pragma unroll
    for (int s = 0; s < 57; ++s) {
        int j = (s << 6) + lane;
        uint q16 = 0xFFFFu;                  // OOB sentinel (strip 56 only)
        if (j < HW) {
            float4 p = sm.tk.pts[j];
            float d2 = fmaxf(sqi + (p.x * p.x + p.y * p.y + p.z * p.z)
                             - 2.0f * (xi * p.x + yi * p.y + zi * p.z), 0.0f);
            q16 = (uint)fminf(d2 * 1024.0f, 65535.0f);
        }
        if (s & 1) qp[s >> 1] |= q16 << 16; else qp[s >> 1] = q16;
    }
    #define Q16(s) ((qp[(s) >> 1] >> (((s) & 1) << 4)) & 0xFFFFu)

    #pragma unroll
    for (int s = 0; s < 57; ++s) {
        int j = (s << 6) + lane;
        if (j < HW) atomicAdd(&sm.tk.hist[wv][Q16(s) >> 8], 1u);
    }
    WAVE_LDS_FENCE();
    wave_select(&sm.tk.hist[wv][0], &sm.tk.s_bin[wv], &sm.tk.s_want[wv], lane, KNN);
    WAVE_LDS_FENCE();
    const uint qT8 = sm.tk.s_bin[wv];
    const uint want2 = sm.tk.s_want[wv];

    #pragma unroll
    for (int s = 0; s < 57; ++s) {
        int j = (s << 6) + lane;
        uint k = Q16(s);
        if (j < HW && (k >> 8) == qT8)
            atomicAdd(&sm.tk.hist[wv][k & 255u], 1u);
    }
    WAVE_LDS_FENCE();
    wave_select(&sm.tk.hist[wv][0], &sm.tk.s_bin[wv], &sm.tk.s_want[wv], lane, want2);
    WAVE_LDS_FENCE();
    const uint qT16 = (qT8 << 8) | sm.tk.s_bin[wv];
    const uint want3 = sm.tk.s_want[wv];

    #pragma unroll
    for (int s = 0; s < 57; ++s) {
        if (Q16(s) < qT16) {
            uint pos = atomicAdd(&sm.tk.s_cnt[wv], 1u);
            if (pos < KNN) idx_out[(size_t)q * KNN + pos] = (s << 6) + lane;
        }
    }

    ull cand[4] = {~0ULL, ~0ULL, ~0ULL, ~0ULL};
    int ncand = 0;
    #pragma unroll
    for (int s = 0; s < 57; ++s) {
        int j = (s << 6) + lane;
        if (j < HW && Q16(s) == qT16) {
            float4 p = sm.tk.pts[j];
            float d2 = fmaxf(sqi + (p.x * p.x + p.y * p.y + p.z * p.z)
                             - 2.0f * (xi * p.x + yi * p.y + zi * p.z), 0.0f);
            ull key = ((ull)__float_as_uint(d2) << 32) | (uint)j;
            if      (ncand == 0) cand[0] = key;
            else if (ncand == 1) cand[1] = key;
            else if (ncand == 2) cand[2] = key;
            else if (ncand == 3) cand[3] = key;
            ++ncand;
        }
    }
    const int base = KNN - (int)want3;
    if (__ballot(ncand > 4) == 0ULL) {
        for (int r = 0; r < (int)want3; ++r) {
            ull best = cand[0] < cand[1] ? cand[0] : cand[1];
            ull b23  = cand[2] < cand[3] ? cand[2] : cand[3];
            best = best < b23 ? best : b23;
            #pragma unroll
            for (int off = 1; off < 64; off <<= 1) {
                ull o = __shfl_xor(best, off, 64);
                if (o < best) best = o;
            }
            if (lane == 0) idx_out[(size_t)q * KNN + base + r] = (int)(uint)best;
            #pragma unroll
            for (int c = 0; c < 4; ++c)
                if (cand[c] == best) cand[c] = ~0ULL;
        }
    } else {
        ull used = 0ULL;
        for (int r = 0; r < (int)want3; ++r) {
            ull best = ~0ULL;
            #pragma unroll
            for (int s = 0; s < 57; ++s) {
                int j = (s << 6) + lane;
                if (j < HW && Q16(s) == qT16 && !((used >> s) & 1ULL)) {
                    float4 p = sm.tk.pts[j];
                    float d2 = fmaxf(sqi + (p.x * p.x + p.y * p.y + p.z * p.z)
                                     - 2.0f * (xi * p.x + yi * p.y + zi * p.z), 0.0f);
                    ull key = ((ull)__float_as_uint(d2) << 32) | (uint)j;
                    if (key < best) best = key;
                }
            }
            #pragma unroll
            for (int off = 1; off < 64; off <<= 1) {
                ull o = __shfl_xor(best, off, 64);
                if (o < best) best = o;
            }
            uint jw = (uint)best;
            if (lane == 0) idx_out[(size_t)q * KNN + base + r] = (int)jw;
            if ((int)(jw & 63u) == lane) used |= 1ULL << (jw >> 6);
        }
    }
    #undef Q16
}

// ---------------------------------------------------------------------------
// D1: dual GEMM, 904 blocks (verbatim round 5, passed).
// v<452:  Tb = relu(mlp_w . h + mb)   [bf16]
// v>=452: P  = Wh . h + rb            [fp32, no relu]  (Wh = rnn_w k 0..255)
// ---------------------------------------------------------------------------
__global__ __launch_bounds__(256) void gemm_dual(
    const unsigned short* __restrict__ NH,
    const unsigned short* __restrict__ mwb,  // mlp weights bf16, ldw 256
    const float* __restrict__ mbias,
    const unsigned short* __restrict__ rwb,  // rnn weights bf16, ldw 512
    const float* __restrict__ rbias,
    unsigned short* __restrict__ Tb,         // ldc 256
    float* __restrict__ P) {                 // ldc 256
    __shared__ __align__(16) unsigned short As[64 * LDB2];
    __shared__ __align__(16) unsigned short Bs[64 * LDB2];
    const int v = blockIdx.x;
    const bool is_mlp = v < 452;
    const int g = is_mlp ? v : v - 452;
    const int m0 = (g % 113) * 64;
    const int n0 = (g / 113) * 64;
    const unsigned short* __restrict__ W = is_mlp ? mwb : rwb;
    const int ldw = is_mlp ? 256 : 512;

    const int tid = threadIdx.x;
    const int lane = tid & 63;
    const int w = tid >> 6;
    const int wm = (w & 1) * 32;
    const int wn = (w >> 1) * 32;
    const int l15 = lane & 15;
    const int qd = lane >> 4;                // quad 0..3

    floatx4 acc[2][2];
    #pragma unroll
    for (int a = 0; a < 2; ++a)
        #pragma unroll
        for (int b = 0; b < 2; ++b)
            acc[a][b] = (floatx4){0.f, 0.f, 0.f, 0.f};

    const int srow = tid >> 4;               // 0..15
    const int scol = (tid & 15) * 8;         // 16B chunks across 128 cols

    for (int kc = 0; kc < 256; kc += 128) {
        if (kc) __syncthreads();
        #pragma unroll
        for (int r4 = 0; r4 < 4; ++r4) {
            int row = r4 * 16 + srow;
            *(float4*)&As[row * LDB2 + scol] =
                *(const float4*)&NH[(size_t)(m0 + row) * 512 + kc + scol];
            *(float4*)&Bs[row * LDB2 + scol] =
                *(const float4*)&W[(size_t)(n0 + row) * ldw + kc + scol];
        }
        __syncthreads();
        #pragma unroll
        for (int ks = 0; ks < 128; ks += 32) {
            short8 a0 = *(const short8*)&As[(wm + l15) * LDB2 + ks + qd * 8];
            short8 a1 = *(const short8*)&As[(wm + 16 + l15) * LDB2 + ks + qd * 8];
            short8 b0 = *(const short8*)&Bs[(wn + l15) * LDB2 + ks + qd * 8];
            short8 b1 = *(const short8*)&Bs[(wn + 16 + l15) * LDB2 + ks + qd * 8];
            acc[0][0] = __builtin_amdgcn_mfma_f32_16x16x32_bf16(a0, b0, acc[0][0], 0, 0, 0);
            acc[0][1] = __builtin_amdgcn_mfma_f32_16x16x32_bf16(a0, b1, acc[0][1], 0, 0, 0);
            acc[1][0] = __builtin_amdgcn_mfma_f32_16x16x32_bf16(a1, b0, acc[1][0], 0, 0, 0);
            acc[1][1] = __builtin_amdgcn_mfma_f32_16x16x32_bf16(a1, b1, acc[1][1], 0, 0, 0);
        }
    }

    #pragma unroll
    for (int in = 0; in < 2; ++in) {
        int col = n0 + wn + in * 16 + l15;
        float bv = is_mlp ? mbias[col] : rbias[col];
        #pragma unroll
        for (int im = 0; im < 2; ++im) {
            int mb = m0 + wm + im * 16 + qd * 4;
            if (is_mlp) {
                #pragma unroll
                for (int r = 0; r < 4; ++r)
                    Tb[(size_t)(mb + r) * CDIM + col] =
                        f2bf(fmaxf(acc[im][in][r] + bv, 0.0f));
            } else {
                #pragma unroll
                for (int r = 0; r < 4; ++r)
                    P[(size_t)(mb + r) * CDIM + col] = acc[im][in][r] + bv;
            }
        }
    }
}

// ---------------------------------------------------------------------------
// gather_gemm (fused D2+D3): block owns 16 query rows.
//  phase 1: gather msg[16][256] = mean_k Tb[idx] into LDS (fp32 accum, bf16
//           round — bit-identical to old gather_mean). 4 waves x 4 queries,
//           4-query-interleaved inner loop keeps 16 uint4 loads in flight.
//  phase 2: h'[16][256] = relu(msg . Wm^T + P), Wm staged in 4 n-chunks of
//           64. Same MFMA k-order as old gemm_rnn2 -> bit-identical.
// mode 0: bf16 store into NH left half; mode 1: fp32 transpose-store to out.
// No in-place hazard: reads Tb/P/idx only. LDS 42 KB -> 3 blocks/CU.
// ---------------------------------------------------------------------------
__global__ __launch_bounds__(256) void gather_gemm(
    const unsigned short* __restrict__ T,    // Tb, ld 256
    const int* __restrict__ idx,
    const float* __restrict__ P,             // ld 256
    const unsigned short* __restrict__ rwb,  // rnn weights bf16 ld 512 (Wm = cols 256..511)
    unsigned short* __restrict__ NH,         // ld 512 (mode 0 dest)
    float* __restrict__ outp, int mode) {
    __shared__ __align__(16) unsigned short As[16][LDG];
    __shared__ __align__(16) unsigned short Bs[64][LDG];

    const int m0 = blockIdx.x * 16;          // 0..7184; all rows < 7200
    const int tid = threadIdx.x;
    const int lane = tid & 63;
    const int wv = tid >> 6;                 // 0..3
    const int half = lane >> 5;              // k parity
    const int c8 = (lane & 31) * 8;          // 8-col strip
    const int n = m0 / HW;                   // batch (3600%16==0: no straddle)

    // ---- phase 1: gather ----
    int nbr[4];
    #pragma unroll
    for (int qi = 0; qi < 4; ++qi)
        nbr[qi] = idx[(size_t)(m0 + wv * 4 + qi) * KNN + lane];
    float acc[4][8];
    #pragma unroll
    for (int qi = 0; qi < 4; ++qi)
        #pragma unroll
        for (int c = 0; c < 8; ++c) acc[qi][c] = 0.0f;

    #pragma unroll 4
    for (int it = 0; it < 32; ++it) {
        int k = 2 * it + half;
        #pragma unroll
        for (int qi = 0; qi < 4; ++qi) {
            int j = __shfl(nbr[qi], k, 64);
            j = min(max(j, 0), HW - 1);      // defensive clamp
            uint4 v = *(const uint4*)&T[(size_t)(n * HW + j) * CDIM + c8];
            acc[qi][0] += bf2f((unsigned short)(v.x & 0xFFFFu));
            acc[qi][1] += bf2f((unsigned short)(v.x >> 16));
            acc[qi][2] += bf2f((unsigned short)(v.y & 0xFFFFu));
            acc[qi][3] += bf2f((unsigned short)(v.y >> 16));
            acc[qi][4] += bf2f((unsigned short)(v.z & 0xFFFFu));
            acc[qi][5] += bf2f((unsigned short)(v.z >> 16));
            acc[qi][6] += bf2f((unsigned short)(v.w & 0xFFFFu));
            acc[qi][7] += bf2f((unsigned short)(v.w >> 16));
        }
    }
    #pragma unroll
    for (int qi = 0; qi < 4; ++qi) {
        #pragma unroll
        for (int c = 0; c < 8; ++c)
            acc[qi][c] += __shfl_xor(acc[qi][c], 32, 64);
        if (half == 0) {
            uint4 o;
            o.x = (uint)f2bf(acc[qi][0] * (1.0f / KNN)) | ((uint)f2bf(acc[qi][1] * (1.0f / KNN)) << 16);
            o.y = (uint)f2bf(acc[qi][2] * (1.0f / KNN)) | ((uint)f2bf(acc[qi][3] * (1.0f / KNN)) << 16);
            o.z = (uint)f2bf(acc[qi][4] * (1.0f / KNN)) | ((uint)f2bf(acc[qi][5] * (1.0f / KNN)) << 16);
            o.w = (uint)f2bf(acc[qi][6] * (1.0f / KNN)) | ((uint)f2bf(acc[qi][7] * (1.0f / KNN)) << 16);
            *(uint4*)&As[wv * 4 + qi][c8] = o;
        }
    }
    __syncthreads();

    // ---- phase 2: GEMM over 4 n-chunks of 64 output cols ----
    const int l15 = lane & 15;
    const int qd = lane >> 4;
    const int brow = tid >> 2;               // 0..63 (Bs stage row)
    const int bseg = (tid & 3) * 64;         // 64-col strip
    for (int nc = 0; nc < 4; ++nc) {
        if (nc) __syncthreads();
        const unsigned short* __restrict__ src =
            &rwb[(size_t)(nc * 64 + brow) * 512 + 256 + bseg];
        #pragma unroll
        for (int u = 0; u < 8; ++u)
            *(float4*)&Bs[brow][bseg + u * 8] = *(const float4*)&src[u * 8];
        __syncthreads();

        floatx4 o = (floatx4){0.f, 0.f, 0.f, 0.f};
        #pragma unroll
        for (int ks = 0; ks < 256; ks += 32) {
            short8 a = *(const short8*)&As[l15][ks + qd * 8];
            short8 b = *(const short8*)&Bs[wv * 16 + l15][ks + qd * 8];
            o = __builtin_amdgcn_mfma_f32_16x16x32_bf16(a, b, o, 0, 0, 0);
        }
        const int col = nc * 64 + wv * 16 + l15;
        const int mb = m0 + qd * 4;
        if (mode == 0) {
            #pragma unroll
            for (int r = 0; r < 4; ++r) {
                float hv = fmaxf(o[r] + P[(size_t)(mb + r) * CDIM + col], 0.0f);
                NH[(size_t)(mb + r) * 512 + col] = f2bf(hv);
            }
        } else {
            int hw = mb - n * HW;
            float4 ov;
            ov.x = fmaxf(o[0] + P[(size_t)(mb + 0) * CDIM + col], 0.0f);
            ov.y = fmaxf(o[1] + P[(size_t)(mb + 1) * CDIM + col], 0.0f);
            ov.z = fmaxf(o[2] + P[(size_t)(mb + 2) * CDIM + col], 0.0f);
            ov.w = fmaxf(o[3] + P[(size_t)(mb + 3) * CDIM + col], 0.0f);
            *(float4*)&outp[(size_t)n * (2 * CDIM * HW)
                            + (size_t)(CDIM + col) * HW + hw] = ov;
        }
    }
}

extern "C" void kernel_launch(void* const* d_in, const int* in_sizes, int n_in,
                              void* d_out, int out_size, void* d_ws, size_t ws_size,
                              hipStream_t stream) {
    const float* cnn   = (const float*)d_in[0];
    const float* pts   = (const float*)d_in[1];
    const float* mlp_w = (const float*)d_in[2];
    const float* mlp_b = (const float*)d_in[3];
    const float* rnn_w = (const float*)d_in[4];
    const float* rnn_b = (const float*)d_in[5];
    float* out = (float*)d_out;

    // workspace (footprint identical to round 5):
    // NHa(7232x512 u16) | P(7232x256 f32) | Tb(7232x256 u16)
    // | mlpw_b(65536 u16) | rnnw_b(131072 u16) | idx(7200x64 int)
    // msg never hits global memory anymore (lives in gather_gemm's LDS);
    // NH right half is simply unused after init.
    unsigned short* NHa    = (unsigned short*)d_ws;
    float*          P      = (float*)(NHa + (size_t)PADM * 512);
    unsigned short* Tb     = (unsigned short*)(P + (size_t)PADM * CDIM);
    unsigned short* mlpw_b = Tb + (size_t)PADM * CDIM;
    unsigned short* rnnw_b = mlpw_b + 65536;
    int*            idx    = (int*)(rnnw_b + 131072);

    mega_kernel<<<TKB + IHB + SUB, 512, 0, stream>>>(
        pts, idx, cnn, NHa, out, mlp_w, rnn_w, mlpw_b, rnnw_b);

    for (int it = 0; it < 3; ++it) {
        // D1: Tb = relu(mlp_w.h + mb)  AND  P = Wh.h + rb   (one dispatch)
        gemm_dual<<<904, 256, 0, stream>>>(
            NHa, mlpw_b, mlp_b, rnnw_b, rnn_b, Tb, P);
        // GG: h' = relu(Wm.mean_k(Tb[idx]) + P)  (fused gather + GEMM)
        gather_gemm<<<GGB, 256, 0, stream>>>(
            Tb, idx, P, rnnw_b, NHa, out, it == 2 ? 1 : 0);
    }
}

// Round 7
// 206.799 us; speedup vs baseline: 1.4320x; 1.4320x over previous
//
#include <hip/hip_runtime.h>
#include <stdint.h>

typedef unsigned int uint;
typedef unsigned long long ull;

#define HW 3600
#define CDIM 256
#define KNN 64
#define M_REAL 7200
#define PADM 7232          // 7200 padded to multiple of 64 (113*64)
#define QPB 8              // topk queries per block (one per wave)

#define TKB 900            // topk blocks
#define IHB 904            // init_h blocks (2 c-tiles each)
#define SUB 64             // setup blocks

#define LDB2 136           // BK=128 LDS row pitch (shorts)

using short8  = __attribute__((ext_vector_type(8))) short;
using floatx4 = __attribute__((ext_vector_type(4))) float;

__device__ inline unsigned short f2bf(float f) {   // RNE fp32 -> bf16 bits
    uint u = __float_as_uint(f);
    uint r = u + 0x7FFFu + ((u >> 16) & 1u);
    return (unsigned short)(r >> 16);
}
__device__ inline float bf2f(unsigned short b) {
    return __uint_as_float(((uint)b) << 16);
}

#define WAVE_LDS_FENCE() asm volatile("s_waitcnt lgkmcnt(0)" ::: "memory")

// ---------------------------------------------------------------------------
// wave_select2: threshold byte-bin from a 2-replica 256-bin wave-private
// histogram (replica = lane half; summed here, so totals are exact).
// ---------------------------------------------------------------------------
__device__ inline void wave_select2(uint (*H)[256], uint* s_bin, uint* s_want,
                                    int lane, uint want) {
    uint h0 = H[0][4 * lane + 0] + H[1][4 * lane + 0];
    uint h1 = H[0][4 * lane + 1] + H[1][4 * lane + 1];
    uint h2 = H[0][4 * lane + 2] + H[1][4 * lane + 2];
    uint h3 = H[0][4 * lane + 3] + H[1][4 * lane + 3];
    H[0][4 * lane + 0] = 0; H[0][4 * lane + 1] = 0;
    H[0][4 * lane + 2] = 0; H[0][4 * lane + 3] = 0;
    H[1][4 * lane + 0] = 0; H[1][4 * lane + 1] = 0;
    H[1][4 * lane + 2] = 0; H[1][4 * lane + 3] = 0;
    uint c4 = h0 + h1 + h2 + h3;
    uint v = c4;
    #pragma unroll
    for (int off = 1; off < 64; off <<= 1) {
        uint o = __shfl_up(v, off, 64);
        if (lane >= off) v += o;
    }
    uint below = v - c4;
    if (below < want && want <= v) {
        uint b = 4 * lane, c = below;
        if (c + h0 < want) { c += h0; b = 4 * lane + 1;
            if (c + h1 < want) { c += h1; b = 4 * lane + 2;
                if (c + h2 < want) { c += h2; b = 4 * lane + 3; } } }
        *s_bin = b;
        *s_want = want - c;
    }
}

// ---------------------------------------------------------------------------
// Mega-kernel: round-0 structure; topk micro-opts this round:
//  (1) pts.w = |p|^2 precomputed at staging (saves 3 VALU x 57 x 8 waves)
//  (2) hist[wv][2][256] half-wave replicas (halves same-bin atomic depth)
// LDS 74.1 KB -> still 2 blocks/CU. Roles: topk/init_h/setup as before.
// ---------------------------------------------------------------------------
union MegaSmem {
    struct {
        float4 pts[HW];                  // 57600 B (x,y,z,|p|^2)
        uint hist[QPB][2][256];          // 16384 B
        uint s_bin[QPB], s_want[QPB], s_cnt[QPB];
    } tk;
    struct { float tile[2][32][33]; } ih;
};

__global__ __launch_bounds__(512) void mega_kernel(
    const float* __restrict__ points, int* __restrict__ idx_out,
    const float* __restrict__ cnn, unsigned short* __restrict__ NH,
    float* __restrict__ out,
    const float* __restrict__ mw, const float* __restrict__ rw,
    unsigned short* __restrict__ mo, unsigned short* __restrict__ ro) {
    __shared__ MegaSmem sm;
    const int blk = blockIdx.x;

    if (blk >= TKB + IHB) {
        // ---- setup role: weights fp32 -> bf16 ----
        int i0 = (blk - TKB - IHB) * 2048 + threadIdx.x * 4;
        float4 v = *(const float4*)&rw[i0];
        uint2 p;
        p.x = (uint)f2bf(v.x) | ((uint)f2bf(v.y) << 16);
        p.y = (uint)f2bf(v.z) | ((uint)f2bf(v.w) << 16);
        *(uint2*)&ro[i0] = p;
        if (i0 < 65536) {
            float4 m = *(const float4*)&mw[i0];
            p.x = (uint)f2bf(m.x) | ((uint)f2bf(m.y) << 16);
            p.y = (uint)f2bf(m.z) | ((uint)f2bf(m.w) << 16);
            *(uint2*)&mo[i0] = p;
        }
        return;
    }

    if (blk >= TKB) {
        // ---- init_h role: two 32x32 c-tiles per block ----
        const int b = blk - TKB;             // 0..903
        const int n = b / 452;
        const int r = b - n * 452;
        const int hw0 = (r % 113) * 32;
        const int c0 = (r / 113) * 64 + ((threadIdx.x >> 8) << 5);
        const int t8 = threadIdx.x & 255;
        const int tx = t8 & 31;
        const int ty = t8 >> 5;              // 0..7
        float (*tile)[33] = sm.ih.tile[threadIdx.x >> 8];
        const float* __restrict__ src = cnn + (size_t)n * CDIM * HW;
        #pragma unroll
        for (int rr = 0; rr < 4; ++rr) {
            int cc = ty + rr * 8;
            int hw = hw0 + tx;
            if (hw < HW) {
                float v = src[(size_t)(c0 + cc) * HW + hw];
                tile[cc][tx] = v;
                out[(size_t)n * (2 * CDIM * HW) + (size_t)(c0 + cc) * HW + hw] = v;
            }
        }
        __syncthreads();
        #pragma unroll
        for (int rr = 0; rr < 4; ++rr) {
            int hh = ty + rr * 8;
            int hw = hw0 + hh;
            if (hw < HW)
                NH[(size_t)(n * HW + hw) * 512 + c0 + tx] = f2bf(tile[tx][hh]);
        }
        return;
    }

    // ---- topk role ----
    const int wv = threadIdx.x >> 6;
    const int lane = threadIdx.x & 63;
    const int rep = lane >> 5;               // histogram replica
    const int q = blk * QPB + wv;
    const int n = (blk * QPB) / HW;          // batch uniform per block (450 | 8)
    const int i = q - n * HW;

    const float* __restrict__ px = points + (size_t)n * 3 * HW;
    const float* __restrict__ py = px + HW;
    const float* __restrict__ pz = py + HW;

    for (int j = threadIdx.x; j < HW; j += 512) {
        float x = px[j], y = py[j], z = pz[j];
        sm.tk.pts[j] = make_float4(x, y, z, x * x + y * y + z * z);
    }
    sm.tk.hist[wv][0][4 * lane + 0] = 0; sm.tk.hist[wv][0][4 * lane + 1] = 0;
    sm.tk.hist[wv][0][4 * lane + 2] = 0; sm.tk.hist[wv][0][4 * lane + 3] = 0;
    sm.tk.hist[wv][1][4 * lane + 0] = 0; sm.tk.hist[wv][1][4 * lane + 1] = 0;
    sm.tk.hist[wv][1][4 * lane + 2] = 0; sm.tk.hist[wv][1][4 * lane + 3] = 0;
    if (lane == 0) sm.tk.s_cnt[wv] = 0;
    __syncthreads();          // the ONLY block barrier: pts is block-shared

    float4 pq = sm.tk.pts[i];
    const float xi = pq.x, yi = pq.y, zi = pq.z;
    const float sqi = pq.w;

    uint qp[29];
    #pragma unroll
    for (int s = 0; s < 57; ++s) {
        int j = (s << 6) + lane;
        uint q16 = 0xFFFFu;                  // OOB sentinel (strip 56 only)
        if (j < HW) {
            float4 p = sm.tk.pts[j];
            float d2 = fmaxf(sqi + p.w
                             - 2.0f * (xi * p.x + yi * p.y + zi * p.z), 0.0f);
            q16 = (uint)fminf(d2 * 1024.0f, 65535.0f);
        }
        if (s & 1) qp[s >> 1] |= q16 << 16; else qp[s >> 1] = q16;
    }
    #define Q16(s) ((qp[(s) >> 1] >> (((s) & 1) << 4)) & 0xFFFFu)

    #pragma unroll
    for (int s = 0; s < 57; ++s) {
        int j = (s << 6) + lane;
        if (j < HW) atomicAdd(&sm.tk.hist[wv][rep][Q16(s) >> 8], 1u);
    }
    WAVE_LDS_FENCE();
    wave_select2(sm.tk.hist[wv], &sm.tk.s_bin[wv], &sm.tk.s_want[wv], lane, KNN);
    WAVE_LDS_FENCE();
    const uint qT8 = sm.tk.s_bin[wv];
    const uint want2 = sm.tk.s_want[wv];

    #pragma unroll
    for (int s = 0; s < 57; ++s) {
        int j = (s << 6) + lane;
        uint k = Q16(s);
        if (j < HW && (k >> 8) == qT8)
            atomicAdd(&sm.tk.hist[wv][rep][k & 255u], 1u);
    }
    WAVE_LDS_FENCE();
    wave_select2(sm.tk.hist[wv], &sm.tk.s_bin[wv], &sm.tk.s_want[wv], lane, want2);
    WAVE_LDS_FENCE();
    const uint qT16 = (qT8 << 8) | sm.tk.s_bin[wv];
    const uint want3 = sm.tk.s_want[wv];

    #pragma unroll
    for (int s = 0; s < 57; ++s) {
        if (Q16(s) < qT16) {
            uint pos = atomicAdd(&sm.tk.s_cnt[wv], 1u);
            if (pos < KNN) idx_out[(size_t)q * KNN + pos] = (s << 6) + lane;
        }
    }

    ull cand[4] = {~0ULL, ~0ULL, ~0ULL, ~0ULL};
    int ncand = 0;
    #pragma unroll
    for (int s = 0; s < 57; ++s) {
        int j = (s << 6) + lane;
        if (j < HW && Q16(s) == qT16) {
            float4 p = sm.tk.pts[j];
            float d2 = fmaxf(sqi + p.w
                             - 2.0f * (xi * p.x + yi * p.y + zi * p.z), 0.0f);
            ull key = ((ull)__float_as_uint(d2) << 32) | (uint)j;
            if      (ncand == 0) cand[0] = key;
            else if (ncand == 1) cand[1] = key;
            else if (ncand == 2) cand[2] = key;
            else if (ncand == 3) cand[3] = key;
            ++ncand;
        }
    }
    const int base = KNN - (int)want3;
    if (__ballot(ncand > 4) == 0ULL) {
        for (int r = 0; r < (int)want3; ++r) {
            ull best = cand[0] < cand[1] ? cand[0] : cand[1];
            ull b23  = cand[2] < cand[3] ? cand[2] : cand[3];
            best = best < b23 ? best : b23;
            #pragma unroll
            for (int off = 1; off < 64; off <<= 1) {
                ull o = __shfl_xor(best, off, 64);
                if (o < best) best = o;
            }
            if (lane == 0) idx_out[(size_t)q * KNN + base + r] = (int)(uint)best;
            #pragma unroll
            for (int c = 0; c < 4; ++c)
                if (cand[c] == best) cand[c] = ~0ULL;
        }
    } else {
        ull used = 0ULL;
        for (int r = 0; r < (int)want3; ++r) {
            ull best = ~0ULL;
            #pragma unroll
            for (int s = 0; s < 57; ++s) {
                int j = (s << 6) + lane;
                if (j < HW && Q16(s) == qT16 && !((used >> s) & 1ULL)) {
                    float4 p = sm.tk.pts[j];
                    float d2 = fmaxf(sqi + p.w
                                     - 2.0f * (xi * p.x + yi * p.y + zi * p.z), 0.0f);
                    ull key = ((ull)__float_as_uint(d2) << 32) | (uint)j;
                    if (key < best) best = key;
                }
            }
            #pragma unroll
            for (int off = 1; off < 64; off <<= 1) {
                ull o = __shfl_xor(best, off, 64);
                if (o < best) best = o;
            }
            uint jw = (uint)best;
            if (lane == 0) idx_out[(size_t)q * KNN + base + r] = (int)jw;
            if ((int)(jw & 63u) == lane) used |= 1ULL << (jw >> 6);
        }
    }
    #undef Q16
}

// ---------------------------------------------------------------------------
// D1: dual GEMM, 904 blocks (verbatim round 5, passed).
// v<452:  Tb = relu(mlp_w . h + mb)   [bf16]
// v>=452: P  = Wh . h + rb            [fp32, no relu]  (Wh = rnn_w k 0..255)
// ---------------------------------------------------------------------------
__global__ __launch_bounds__(256) void gemm_dual(
    const unsigned short* __restrict__ NH,
    const unsigned short* __restrict__ mwb,  // mlp weights bf16, ldw 256
    const float* __restrict__ mbias,
    const unsigned short* __restrict__ rwb,  // rnn weights bf16, ldw 512
    const float* __restrict__ rbias,
    unsigned short* __restrict__ Tb,         // ldc 256
    float* __restrict__ P) {                 // ldc 256
    __shared__ __align__(16) unsigned short As[64 * LDB2];
    __shared__ __align__(16) unsigned short Bs[64 * LDB2];
    const int v = blockIdx.x;
    const bool is_mlp = v < 452;
    const int g = is_mlp ? v : v - 452;
    const int m0 = (g % 113) * 64;
    const int n0 = (g / 113) * 64;
    const unsigned short* __restrict__ W = is_mlp ? mwb : rwb;
    const int ldw = is_mlp ? 256 : 512;

    const int tid = threadIdx.x;
    const int lane = tid & 63;
    const int w = tid >> 6;
    const int wm = (w & 1) * 32;
    const int wn = (w >> 1) * 32;
    const int l15 = lane & 15;
    const int qd = lane >> 4;                // quad 0..3

    floatx4 acc[2][2];
    #pragma unroll
    for (int a = 0; a < 2; ++a)
        #pragma unroll
        for (int b = 0; b < 2; ++b)
            acc[a][b] = (floatx4){0.f, 0.f, 0.f, 0.f};

    const int srow = tid >> 4;               // 0..15
    const int scol = (tid & 15) * 8;         // 16B chunks across 128 cols

    for (int kc = 0; kc < 256; kc += 128) {
        if (kc) __syncthreads();
        #pragma unroll
        for (int r4 = 0; r4 < 4; ++r4) {
            int row = r4 * 16 + srow;
            *(float4*)&As[row * LDB2 + scol] =
                *(const float4*)&NH[(size_t)(m0 + row) * 512 + kc + scol];
            *(float4*)&Bs[row * LDB2 + scol] =
                *(const float4*)&W[(size_t)(n0 + row) * ldw + kc + scol];
        }
        __syncthreads();
        #pragma unroll
        for (int ks = 0; ks < 128; ks += 32) {
            short8 a0 = *(const short8*)&As[(wm + l15) * LDB2 + ks + qd * 8];
            short8 a1 = *(const short8*)&As[(wm + 16 + l15) * LDB2 + ks + qd * 8];
            short8 b0 = *(const short8*)&Bs[(wn + l15) * LDB2 + ks + qd * 8];
            short8 b1 = *(const short8*)&Bs[(wn + 16 + l15) * LDB2 + ks + qd * 8];
            acc[0][0] = __builtin_amdgcn_mfma_f32_16x16x32_bf16(a0, b0, acc[0][0], 0, 0, 0);
            acc[0][1] = __builtin_amdgcn_mfma_f32_16x16x32_bf16(a0, b1, acc[0][1], 0, 0, 0);
            acc[1][0] = __builtin_amdgcn_mfma_f32_16x16x32_bf16(a1, b0, acc[1][0], 0, 0, 0);
            acc[1][1] = __builtin_amdgcn_mfma_f32_16x16x32_bf16(a1, b1, acc[1][1], 0, 0, 0);
        }
    }

    #pragma unroll
    for (int in = 0; in < 2; ++in) {
        int col = n0 + wn + in * 16 + l15;
        float bv = is_mlp ? mbias[col] : rbias[col];
        #pragma unroll
        for (int im = 0; im < 2; ++im) {
            int mb = m0 + wm + im * 16 + qd * 4;
            if (is_mlp) {
                #pragma unroll
                for (int r = 0; r < 4; ++r)
                    Tb[(size_t)(mb + r) * CDIM + col] =
                        f2bf(fmaxf(acc[im][in][r] + bv, 0.0f));
            } else {
                #pragma unroll
                for (int r = 0; r < 4; ++r)
                    P[(size_t)(mb + r) * CDIM + col] = acc[im][in][r] + bv;
            }
        }
    }
}

// ---------------------------------------------------------------------------
// D3: rnn second half, 452 blocks (verbatim round 5, passed).
// acc = Wm . msg (K=256); h' = relu(acc + P). mode 0: bf16 store to NH LEFT
// half (in-place; reads only right half). mode 1: fp32 transpose-store to out.
// ---------------------------------------------------------------------------
__global__ __launch_bounds__(256) void gemm_rnn2(
    const unsigned short* __restrict__ NH,   // A = NH right half (lda 512)
    const unsigned short* __restrict__ rwb,  // Wm = rnn_w k-cols 256..511
    const float* __restrict__ P,
    unsigned short* __restrict__ Cb,         // NH base (ldc 512), mode 0
    float* __restrict__ outp, int mode) {
    __shared__ __align__(16) unsigned short As[64 * LDB2];
    __shared__ __align__(16) unsigned short Bs[64 * LDB2];
    const int m0 = (blockIdx.x % 113) * 64;
    const int n0 = (blockIdx.x / 113) * 64;

    const int tid = threadIdx.x;
    const int lane = tid & 63;
    const int w = tid >> 6;
    const int wm = (w & 1) * 32;
    const int wn = (w >> 1) * 32;
    const int l15 = lane & 15;
    const int qd = lane >> 4;

    floatx4 acc[2][2];
    #pragma unroll
    for (int a = 0; a < 2; ++a)
        #pragma unroll
        for (int b = 0; b < 2; ++b)
            acc[a][b] = (floatx4){0.f, 0.f, 0.f, 0.f};

    const int srow = tid >> 4;
    const int scol = (tid & 15) * 8;

    for (int kc = 0; kc < 256; kc += 128) {
        if (kc) __syncthreads();
        #pragma unroll
        for (int r4 = 0; r4 < 4; ++r4) {
            int row = r4 * 16 + srow;
            *(float4*)&As[row * LDB2 + scol] =
                *(const float4*)&NH[(size_t)(m0 + row) * 512 + 256 + kc + scol];
            *(float4*)&Bs[row * LDB2 + scol] =
                *(const float4*)&rwb[(size_t)(n0 + row) * 512 + 256 + kc + scol];
        }
        __syncthreads();
        #pragma unroll
        for (int ks = 0; ks < 128; ks += 32) {
            short8 a0 = *(const short8*)&As[(wm + l15) * LDB2 + ks + qd * 8];
            short8 a1 = *(const short8*)&As[(wm + 16 + l15) * LDB2 + ks + qd * 8];
            short8 b0 = *(const short8*)&Bs[(wn + l15) * LDB2 + ks + qd * 8];
            short8 b1 = *(const short8*)&Bs[(wn + 16 + l15) * LDB2 + ks + qd * 8];
            acc[0][0] = __builtin_amdgcn_mfma_f32_16x16x32_bf16(a0, b0, acc[0][0], 0, 0, 0);
            acc[0][1] = __builtin_amdgcn_mfma_f32_16x16x32_bf16(a0, b1, acc[0][1], 0, 0, 0);
            acc[1][0] = __builtin_amdgcn_mfma_f32_16x16x32_bf16(a1, b0, acc[1][0], 0, 0, 0);
            acc[1][1] = __builtin_amdgcn_mfma_f32_16x16x32_bf16(a1, b1, acc[1][1], 0, 0, 0);
        }
    }

    #pragma unroll
    for (int in = 0; in < 2; ++in) {
        int col = n0 + wn + in * 16 + l15;
        #pragma unroll
        for (int im = 0; im < 2; ++im) {
            int mb = m0 + wm + im * 16 + qd * 4;
            if (mode == 0) {
                #pragma unroll
                for (int r = 0; r < 4; ++r) {
                    float o = fmaxf(acc[im][in][r] + P[(size_t)(mb + r) * CDIM + col], 0.0f);
                    Cb[(size_t)(mb + r) * 512 + col] = f2bf(o);
                }
            } else if (mb < M_REAL) {
                int nb = mb / HW;
                int hw = mb - nb * HW;
                float4 o;
                o.x = fmaxf(acc[im][in][0] + P[(size_t)(mb + 0) * CDIM + col], 0.0f);
                o.y = fmaxf(acc[im][in][1] + P[(size_t)(mb + 1) * CDIM + col], 0.0f);
                o.z = fmaxf(acc[im][in][2] + P[(size_t)(mb + 2) * CDIM + col], 0.0f);
                o.w = fmaxf(acc[im][in][3] + P[(size_t)(mb + 3) * CDIM + col], 0.0f);
                *(float4*)&outp[(size_t)nb * (2 * CDIM * HW)
                                + (size_t)(CDIM + col) * HW + hw] = o;
            }
        }
    }
}

// ---------------------------------------------------------------------------
// message[q][c] = (1/64)*sum_k T[n*HW+idx[q][k]][c] -> NH right half (bf16)
// (verbatim round 5, passed)
// ---------------------------------------------------------------------------
__global__ __launch_bounds__(256) void gather_mean(const unsigned short* __restrict__ T,
                                                   const int* __restrict__ idx,
                                                   unsigned short* __restrict__ NH) {
    const int q = blockIdx.x * 4 + (threadIdx.x >> 6);
    const int lane = threadIdx.x & 63;
    const int n = q / HW;
    const int half = lane >> 5;           // k parity
    const int c8 = (lane & 31) * 8;       // 8-col strip

    const int nbrL = idx[(size_t)q * KNN + lane];
    float acc[8] = {0, 0, 0, 0, 0, 0, 0, 0};
    #pragma unroll 4
    for (int it = 0; it < 32; ++it) {
        int k = 2 * it + half;
        int j = __shfl(nbrL, k, 64);
        j = min(max(j, 0), HW - 1);       // defensive clamp
        int r = n * HW + j;
        uint4 v = *(const uint4*)&T[(size_t)r * CDIM + c8];
        acc[0] += bf2f((unsigned short)(v.x & 0xFFFFu));
        acc[1] += bf2f((unsigned short)(v.x >> 16));
        acc[2] += bf2f((unsigned short)(v.y & 0xFFFFu));
        acc[3] += bf2f((unsigned short)(v.y >> 16));
        acc[4] += bf2f((unsigned short)(v.z & 0xFFFFu));
        acc[5] += bf2f((unsigned short)(v.z >> 16));
        acc[6] += bf2f((unsigned short)(v.w & 0xFFFFu));
        acc[7] += bf2f((unsigned short)(v.w >> 16));
    }
    #pragma unroll
    for (int c = 0; c < 8; ++c) acc[c] += __shfl_xor(acc[c], 32, 64);
    if (half == 0) {
        uint4 o;
        o.x = (uint)f2bf(acc[0] * (1.0f / KNN)) | ((uint)f2bf(acc[1] * (1.0f / KNN)) << 16);
        o.y = (uint)f2bf(acc[2] * (1.0f / KNN)) | ((uint)f2bf(acc[3] * (1.0f / KNN)) << 16);
        o.z = (uint)f2bf(acc[4] * (1.0f / KNN)) | ((uint)f2bf(acc[5] * (1.0f / KNN)) << 16);
        o.w = (uint)f2bf(acc[6] * (1.0f / KNN)) | ((uint)f2bf(acc[7] * (1.0f / KNN)) << 16);
        *(uint4*)&NH[(size_t)q * 512 + CDIM + c8] = o;
    }
}

extern "C" void kernel_launch(void* const* d_in, const int* in_sizes, int n_in,
                              void* d_out, int out_size, void* d_ws, size_t ws_size,
                              hipStream_t stream) {
    const float* cnn   = (const float*)d_in[0];
    const float* pts   = (const float*)d_in[1];
    const float* mlp_w = (const float*)d_in[2];
    const float* mlp_b = (const float*)d_in[3];
    const float* rnn_w = (const float*)d_in[4];
    const float* rnn_b = (const float*)d_in[5];
    float* out = (float*)d_out;

    // workspace (footprint identical to round 5):
    // NHa(7232x512 u16) | P(7232x256 f32) | Tb(7232x256 u16)
    // | mlpw_b(65536 u16) | rnnw_b(131072 u16) | idx(7200x64 int)
    unsigned short* NHa    = (unsigned short*)d_ws;
    float*          P      = (float*)(NHa + (size_t)PADM * 512);
    unsigned short* Tb     = (unsigned short*)(P + (size_t)PADM * CDIM);
    unsigned short* mlpw_b = Tb + (size_t)PADM * CDIM;
    unsigned short* rnnw_b = mlpw_b + 65536;
    int*            idx    = (int*)(rnnw_b + 131072);

    mega_kernel<<<TKB + IHB + SUB, 512, 0, stream>>>(
        pts, idx, cnn, NHa, out, mlp_w, rnn_w, mlpw_b, rnnw_b);

    for (int it = 0; it < 3; ++it) {
        // D1: Tb = relu(mlp_w.h + mb)  AND  P = Wh.h + rb   (one dispatch)
        gemm_dual<<<904, 256, 0, stream>>>(
            NHa, mlpw_b, mlp_b, rnnw_b, rnn_b, Tb, P);
        // D2: msg = mean_k Tb[idx] -> NHa right half
        gather_mean<<<M_REAL / 4, 256, 0, stream>>>(Tb, idx, NHa);
        // D3: h' = relu(Wm.msg + P)
        if (it < 2) {
            gemm_rnn2<<<452, 256, 0, stream>>>(
                NHa, rnnw_b, P, NHa, nullptr, 0);
        } else {
            gemm_rnn2<<<452, 256, 0, stream>>>(
                NHa, rnnw_b, P, nullptr, out, 1);
        }
    }
}